// Round 6
// baseline (254.584 us; speedup 1.0000x reference)
//
#include <hip/hip_runtime.h>
#include <math.h>

// Problem constants (fixed by reference)
#define GRIDN   14
#define BOXN    2
#define LABELN  20
#define ALL_BOX 10          // 5*BOXN
#define CCH     30          // ALL_BOX + LABELN channels per cell

// Native clang vector type: __builtin_nontemporal_load requires a real
// vector type, not HIP's struct-based float4.
typedef float vfloat4 __attribute__((ext_vector_type(4)));

__global__ void yolo_zero_kernel(float* out, int n) {
    int i = blockIdx.x * blockDim.x + threadIdx.x;
    if (i < n) out[i] = 0.0f;
}

// Validated per-cell loss math (absmax 0 in rounds 1-4). p/t point at the
// cell's 30 channels held in registers (constant indices after inlining ->
// SROA keeps everything in VGPRs; dynamic `resp` handled by scalar selects).
__device__ __forceinline__ float cell_loss(const float* p, const float* t) {
#pragma clang fp contract(off)
    const float CELL = (float)(1.0 / (double)GRIDN);

    const float tx = t[0], ty = t[1], tw = t[2], th_ = t[3], tconf = t[4];
    const bool obj = tconf > 0.0f;

    // Truth box (scaled center, half-extent) — same op order as reference
    const float tcx = CELL * tx, tcy = CELL * ty;
    const float thx = tw * 0.5f, thy = th_ * 0.5f;
    const float tltx = tcx - thx, tlty = tcy - thy;
    const float trbx = tcx + thx, trby = tcy + thy;
    const float ta = (trbx - tltx) * (trby - tlty);

    float iou[BOXN], conf[BOXN];
#pragma unroll
    for (int b = 0; b < BOXN; ++b) {
        const float bx = p[b * 5 + 0], by = p[b * 5 + 1];
        const float bw = p[b * 5 + 2], bh = p[b * 5 + 3];
        conf[b] = p[b * 5 + 4];
        const float pcx = CELL * bx, pcy = CELL * by;
        const float phx = bw * 0.5f, phy = bh * 0.5f;
        const float pltx = pcx - phx, plty = pcy - phy;
        const float prbx = pcx + phx, prby = pcy + phy;
        const float ltx = fmaxf(pltx, tltx), lty = fmaxf(plty, tlty);
        const float rbx = fminf(prbx, trbx), rby = fminf(prby, trby);
        const float whx = fmaxf(rbx - ltx, 0.0f);
        const float why = fmaxf(rby - lty, 0.0f);
        const float inter = whx * why;
        const float pa = (prbx - pltx) * (prby - plty);
        iou[b] = inter / (pa + ta - inter);
    }

    const float max_iou = fmaxf(iou[0], iou[1]);
    // jnp argmax first-occurrence + tie rule (n_tied>1 -> conf argmax)
    bool r1;
    if (iou[0] == iou[1]) r1 = !(conf[0] >= conf[1]);
    else                  r1 = !(iou[0] > iou[1]);

    // resp-box fields via scalar selects (no dynamic array indexing)
    const float rx = r1 ? p[5] : p[0];
    const float ry = r1 ? p[6] : p[1];
    const float rw = r1 ? p[7] : p[2];
    const float rh = r1 ? p[8] : p[3];
    const float rc = r1 ? p[9] : p[4];

    const float dcx = rx - tx;
    const float dcy = ry - ty;
    const float center = dcx * dcx + dcy * dcy;

    const float dsx = sqrtf(rw) - sqrtf(tw);
    const float dsy = sqrtf(rh) - sqrtf(th_);
    const float size = dsx * dsx + dsy * dsy;

    const float dconf = rc - max_iou;
    const float conf_resp = dconf * dconf;

    const float c_other = r1 ? conf[0] : conf[1];
    const float conf_noresp = c_other * c_other;

    const float conf_noobj = conf[0] * conf[0] + conf[1] * conf[1];

    float label = 0.0f;
#pragma unroll
    for (int k = ALL_BOX; k < CCH; ++k) {
        const float d = p[k] - t[k];
        label += d * d;
    }

    const float w  = obj ? 1.0f : 0.0f;
    const float nw = obj ? 0.0f : 1.0f;
    return w * (5.0f * (center + size) + conf_resp + 0.5f * conf_noresp + label)
         + nw * (0.5f * conf_noobj);
}

// R5/R6 theory: the 4-round 1.2-1.6 TB/s plateau across wildly different
// structures fits a per-CU L1 outstanding-miss (MSHR) limit (~0.5-1 KB in
// flight -> ~1.4 TB/s device-wide at HBM latency). This stream has zero
// reuse, so bypass L1 with nontemporal (nt) loads, use 16B-aligned float4
// (2 cells = 240 B per thread), and pin the 30-load burst before compute
// with a scheduling barrier so the compiler can't re-sink loads (round 4's
// VGPR=32 pathology).
__global__ __launch_bounds__(256, 2) void yolo_loss_kernel(
    const float* __restrict__ preds,
    const float* __restrict__ truths,
    float* __restrict__ out,
    int npairs)
{
#pragma clang fp contract(off)
    __shared__ float wsum[4];

    const int tid  = threadIdx.x;
    const int wave = tid >> 6;
    const int lane = tid & 63;

    const long long pair = (long long)blockIdx.x * blockDim.x + tid;

    float loss = 0.0f;
    if (pair < npairs) {
        const vfloat4* pp = (const vfloat4*)(preds  + pair * 60);  // 240B base -> 16B aligned
        const vfloat4* tp = (const vfloat4*)(truths + pair * 60);

        vfloat4 P4[15], T4[15];
#pragma unroll
        for (int i = 0; i < 15; ++i) P4[i] = __builtin_nontemporal_load(&pp[i]);
#pragma unroll
        for (int i = 0; i < 15; ++i) T4[i] = __builtin_nontemporal_load(&tp[i]);
        __builtin_amdgcn_sched_barrier(0);   // all 30 loads issued before compute

        const float* P = (const float*)P4;
        const float* T = (const float*)T4;
        loss = cell_loss(P, T) + cell_loss(P + CCH, T + CCH);
    }

    // Block reduction: wave64 shuffle -> LDS across 4 waves -> one atomic per block
    float v = loss;
#pragma unroll
    for (int off = 32; off > 0; off >>= 1) v += __shfl_down(v, off, 64);
    if (lane == 0) wsum[wave] = v;
    __syncthreads();
    if (tid == 0) {
        const float s = (wsum[0] + wsum[1]) + (wsum[2] + wsum[3]);
        atomicAdd(out, s * (1.0f / 4096.0f));
    }
}

extern "C" void kernel_launch(void* const* d_in, const int* in_sizes, int n_in,
                              void* d_out, int out_size, void* d_ws, size_t ws_size,
                              hipStream_t stream) {
    const float* preds  = (const float*)d_in[0];
    const float* truths = (const float*)d_in[1];
    float* out = (float*)d_out;

    const int ncells = in_sizes[0] / CCH;          // 4096*14*14 = 802816
    const int npairs = ncells / 2;                 // 401408 (exact)
    const int blocks = (npairs + 255) / 256;       // 1568 (exact)

    // d_out is re-poisoned before every timed launch -> zero it on-stream first.
    yolo_zero_kernel<<<(out_size + 255) / 256, 256, 0, stream>>>(out, out_size);
    yolo_loss_kernel<<<blocks, 256, 0, stream>>>(preds, truths, out, npairs);
}

// Round 7
// 204.548 us; speedup vs baseline: 1.2446x; 1.2446x over previous
//
#include <hip/hip_runtime.h>
#include <math.h>

// Problem constants (fixed by reference)
#define GRIDN   14
#define BOXN    2
#define LABELN  20
#define ALL_BOX 10          // 5*BOXN
#define CCH     30          // ALL_BOX + LABELN channels per cell

#define TCELLS  256         // cells per block-tile
#define TF4     1920        // float4 per tensor per tile (256*30/4)
#define VTOT    3840        // virtual float4 per tile (preds+truths)
#define PBLOCKS 512         // persistent blocks (2/CU)

typedef float vfloat4 __attribute__((ext_vector_type(4)));

__global__ void yolo_zero_kernel(float* out, int n) {
    int i = blockIdx.x * blockDim.x + threadIdx.x;
    if (i < n) out[i] = 0.0f;
}

// Validated per-cell loss math (absmax 0 in rounds 1-6).
__device__ __forceinline__ float cell_loss(const float* p, const float* t) {
#pragma clang fp contract(off)
    const float CELL = (float)(1.0 / (double)GRIDN);

    const float tx = t[0], ty = t[1], tw = t[2], th_ = t[3], tconf = t[4];
    const bool obj = tconf > 0.0f;

    const float tcx = CELL * tx, tcy = CELL * ty;
    const float thx = tw * 0.5f, thy = th_ * 0.5f;
    const float tltx = tcx - thx, tlty = tcy - thy;
    const float trbx = tcx + thx, trby = tcy + thy;
    const float ta = (trbx - tltx) * (trby - tlty);

    float iou[BOXN], conf[BOXN];
#pragma unroll
    for (int b = 0; b < BOXN; ++b) {
        const float bx = p[b * 5 + 0], by = p[b * 5 + 1];
        const float bw = p[b * 5 + 2], bh = p[b * 5 + 3];
        conf[b] = p[b * 5 + 4];
        const float pcx = CELL * bx, pcy = CELL * by;
        const float phx = bw * 0.5f, phy = bh * 0.5f;
        const float pltx = pcx - phx, plty = pcy - phy;
        const float prbx = pcx + phx, prby = pcy + phy;
        const float ltx = fmaxf(pltx, tltx), lty = fmaxf(plty, tlty);
        const float rbx = fminf(prbx, trbx), rby = fminf(prby, trby);
        const float whx = fmaxf(rbx - ltx, 0.0f);
        const float why = fmaxf(rby - lty, 0.0f);
        const float inter = whx * why;
        const float pa = (prbx - pltx) * (prby - plty);
        iou[b] = inter / (pa + ta - inter);
    }

    const float max_iou = fmaxf(iou[0], iou[1]);
    bool r1;
    if (iou[0] == iou[1]) r1 = !(conf[0] >= conf[1]);
    else                  r1 = !(iou[0] > iou[1]);

    const float rx = r1 ? p[5] : p[0];
    const float ry = r1 ? p[6] : p[1];
    const float rw = r1 ? p[7] : p[2];
    const float rh = r1 ? p[8] : p[3];
    const float rc = r1 ? p[9] : p[4];

    const float dcx = rx - tx;
    const float dcy = ry - ty;
    const float center = dcx * dcx + dcy * dcy;

    const float dsx = sqrtf(rw) - sqrtf(tw);
    const float dsy = sqrtf(rh) - sqrtf(th_);
    const float size = dsx * dsx + dsy * dsy;

    const float dconf = rc - max_iou;
    const float conf_resp = dconf * dconf;

    const float c_other = r1 ? conf[0] : conf[1];
    const float conf_noresp = c_other * c_other;

    const float conf_noobj = conf[0] * conf[0] + conf[1] * conf[1];

    float label = 0.0f;
#pragma unroll
    for (int k = ALL_BOX; k < CCH; ++k) {
        const float d = p[k] - t[k];
        label += d * d;
    }

    const float w  = obj ? 1.0f : 0.0f;
    const float nw = obj ? 0.0f : 1.0f;
    return w * (5.0f * (center + size) + conf_resp + 0.5f * conf_noresp + label)
         + nw * (0.5f * conf_noobj);
}

// R7: persistent register-prefetch double-buffered pipeline.
//  - All global loads are lane-contiguous float4 (16 lines/instr, each line
//    consumed exactly once) -> no L1 line-amplification, minimal TA work.
//    This is the m13 6.3 TB/s load pattern; rounds 4-6's per-lane 120/240 B
//    strides touched 64 lines/instr and plateaued at ~2.5 TB/s delivered
//    INDEPENDENT of data source (L3-resident replays = same time) -> CU-side
//    request-processing bound, fixed here.
//  - Next tile's 15 float4/thread are loaded into REGISTERS while the current
//    tile is computed from LDS -> loads in flight the whole iteration
//    (~1000+ cyc), no dead phases, no block churn (512 blocks persistent).
__global__ __launch_bounds__(256) void yolo_loss_kernel(
    const float* __restrict__ preds,
    const float* __restrict__ truths,
    float* __restrict__ out,
    int ntiles)
{
#pragma clang fp contract(off)
    __shared__ vfloat4 sbuf[VTOT];      // 61,440 B -> 2 blocks/CU
    __shared__ float wsum[4];

    const int tid  = threadIdx.x;
    const int wave = tid >> 6;
    const int lane = tid & 63;

    const vfloat4* pp = (const vfloat4*)preds;
    const vfloat4* tp = (const vfloat4*)truths;

    vfloat4 R[15];
    int tile = blockIdx.x;

    // Prologue: prefetch first tile (virtual idx: [0,1920)=preds, rest=truths)
    if (tile < ntiles) {
        const long long g = (long long)tile * TF4;
#pragma unroll
        for (int i = 0; i < 15; ++i) {
            const int idx = i * 256 + tid;
            R[i] = (idx < TF4) ? pp[g + idx] : tp[g + (idx - TF4)];
        }
    }

    float acc = 0.0f;
    for (; tile < ntiles; tile += PBLOCKS) {
        const int next = tile + PBLOCKS;

        __syncthreads();                     // prev compute done -> LDS reusable
#pragma unroll
        for (int i = 0; i < 15; ++i)         // ds_write_b128, lane-contiguous
            sbuf[i * 256 + tid] = R[i];

        if (next < ntiles) {                 // issue next tile's loads now;
            const long long g = (long long)next * TF4;   // in flight across compute
#pragma unroll
            for (int i = 0; i < 15; ++i) {
                const int idx = i * 256 + tid;
                R[i] = (idx < TF4) ? pp[g + idx] : tp[g + (idx - TF4)];
            }
        }
        __syncthreads();                     // tile visible to all waves

        const float* sf = (const float*)sbuf;
        acc += cell_loss(sf + tid * CCH, sf + TF4 * 4 + tid * CCH);
    }

    // Per-thread acc -> wave shuffle -> LDS across waves -> one atomic per block
#pragma unroll
    for (int off = 32; off > 0; off >>= 1) acc += __shfl_down(acc, off, 64);
    if (lane == 0) wsum[wave] = acc;
    __syncthreads();
    if (tid == 0) {
        const float s = (wsum[0] + wsum[1]) + (wsum[2] + wsum[3]);
        atomicAdd(out, s * (1.0f / 4096.0f));
    }
}

extern "C" void kernel_launch(void* const* d_in, const int* in_sizes, int n_in,
                              void* d_out, int out_size, void* d_ws, size_t ws_size,
                              hipStream_t stream) {
    const float* preds  = (const float*)d_in[0];
    const float* truths = (const float*)d_in[1];
    float* out = (float*)d_out;

    const int ncells = in_sizes[0] / CCH;      // 802816
    const int ntiles = ncells / TCELLS;        // 3136 (exact)

    yolo_zero_kernel<<<(out_size + 255) / 256, 256, 0, stream>>>(out, out_size);
    yolo_loss_kernel<<<PBLOCKS, 256, 0, stream>>>(preds, truths, out, ntiles);
}